// Round 6
// baseline (305.093 us; speedup 1.0000x reference)
//
#include <hip/hip_runtime.h>

typedef __attribute__((ext_vector_type(8))) short bf16x8;
typedef __attribute__((ext_vector_type(4))) float f32x4;

#define MFMA16(a,b,c) __builtin_amdgcn_mfma_f32_16x16x32_bf16(a,b,c,0,0,0)

__device__ __forceinline__ unsigned short f2bf(float f){
  unsigned int u = __float_as_uint(f);
  unsigned int r = (u + 0x7fffu + ((u >> 16) & 1u)) >> 16;
  return (unsigned short)r;
}
__device__ __forceinline__ float bf2f(unsigned short u){
  return __uint_as_float(((unsigned int)u) << 16);
}
__device__ __forceinline__ bf16x8 cvt8(float4 a, float4 b){
  bf16x8 t;
  t[0] = (short)f2bf(a.x); t[1] = (short)f2bf(a.y);
  t[2] = (short)f2bf(a.z); t[3] = (short)f2bf(a.w);
  t[4] = (short)f2bf(b.x); t[5] = (short)f2bf(b.y);
  t[6] = (short)f2bf(b.z); t[7] = (short)f2bf(b.w);
  return t;
}

// ---------------- wz prep: wz' = wz*w (bf16), c1=sum(wz*w), c2=sum(wz*b) ----------------
__global__ __launch_bounds__(256) void wzprep_kernel(
    const float* __restrict__ wz, const float* __restrict__ znw,
    const float* __restrict__ znb, unsigned short* __restrict__ wzp,
    float* __restrict__ c12)
{
  __shared__ float r1[256], r2[256];
  int t = threadIdx.x; int h = t >> 4; int k0 = (t & 15) * 8;
  float p1 = 0.f, p2 = 0.f;
  for (int e = 0; e < 8; e++) {
    float wv = wz[h*128 + k0 + e];
    float w = znw[k0 + e], b = znb[k0 + e];
    wzp[h*128 + k0 + e] = f2bf(wv * w);
    p1 += wv * w; p2 += wv * b;
  }
  r1[t] = p1; r2[t] = p2;
  __syncthreads();
  if ((t & 15) == 0) {
    float s1 = 0.f, s2 = 0.f;
    for (int i = 0; i < 16; i++) { s1 += r1[t + i]; s2 += r2[t + i]; }
    c12[2*h] = s1; c12[2*h + 1] = s2;
  }
}

// ---------------- bias_stream: bias[h][i][j] = LN(z[i,j,:]) . wz[h,:]  (bf16 out) ----------------
// 512-thr blocks (8 waves), 1 block/CU. Unit = (i, 128 j's): wave w stages its 16
// z-rows (8 KB) via global_load_lds into double-buffered LDS. Deep gll queue ->
// ~64 KB in flight per CU (MLP no longer the limit). LDS reads are conflict-
// optimal via XOR-swizzle: LDS[row][p] = z[row][p ^ ((row&7)<<4)] (pre-swizzled
// global source, linear gll dest; reads apply the same XOR).
__global__ __launch_bounds__(512, 2) void bias_stream(
    const float* __restrict__ z, const unsigned short* __restrict__ wzp,
    const float* __restrict__ c12, unsigned short* __restrict__ bias)
{
  __shared__ __align__(1024) char zbuf[2 * 65536];       // 128 KB: 2 bufs x 8 waves x 8 KB
  __shared__ __align__(16) unsigned short bounce[16][136]; // bias transpose bounce
  int tid = threadIdx.x;
  int w = tid >> 6, lane = tid & 63;
  int jl = lane & 15, g = lane >> 4;
  int half = lane >> 5, lane31 = lane & 31;

  bf16x8 af[4];
  #pragma unroll
  for (int mk = 0; mk < 4; mk++)
    af[mk] = *(const bf16x8*)(wzp + jl*128 + mk*32 + g*8);
  float c1r[4], c2r[4];
  #pragma unroll
  for (int r = 0; r < 4; r++) {
    c1r[r] = c12[2*(g*4 + r)];
    c2r[r] = c12[2*(g*4 + r) + 1];
  }

  const int nsteps = 32;
  int u0 = blockIdx.x * nsteps;

  // stage(u, buf): wave w issues 8 gll-16B covering its 16 rows (8 KB contiguous)
  auto stage = [&](int u, int buf) {
    int i = u >> 3, jh = u & 7;
    const char* gw = (const char*)z + (((size_t)i*1024 + jh*128 + w*16) << 9);
    char* lb = zbuf + buf*65536 + w*8192;
    #pragma unroll
    for (int c = 0; c < 8; c++) {
      int row = c*2 + half;
      unsigned pin = (unsigned)(lane31*16) ^ (unsigned)((row & 7) << 4);
      __builtin_amdgcn_global_load_lds(
          (const unsigned int*)(gw + (size_t)row*512 + pin),
          (unsigned int*)(lb + c*1024), 16, 0, 0);
    }
  };

  stage(u0, 0);
  for (int step = 0; step < nsteps; ++step) {
    int u = u0 + step;
    int buf = step & 1;
    if (step + 1 < nsteps) {
      stage(u0 + step + 1, buf ^ 1);
      asm volatile("s_waitcnt vmcnt(8)" ::: "memory");   // current buf's 8 glls done
    } else {
      asm volatile("s_waitcnt vmcnt(1)" ::: "memory");   // allow last write-out store
    }
    __builtin_amdgcn_sched_barrier(0);

    const char* wb = zbuf + buf*65536 + w*8192;
    unsigned key = (unsigned)((jl & 7) << 4);
    float sum = 0.f, sq = 0.f;
    bf16x8 tf[4];
    #pragma unroll
    for (int mk = 0; mk < 4; mk++) {
      unsigned x = (unsigned)(mk*128 + g*32);
      float4 a = *(const float4*)(wb + jl*512 + (x ^ key));
      float4 b = *(const float4*)(wb + jl*512 + ((x + 16) ^ key));
      sum += a.x + a.y + a.z + a.w + b.x + b.y + b.z + b.w;
      sq = fmaf(a.x, a.x, fmaf(a.y, a.y, fmaf(a.z, a.z, fmaf(a.w, a.w, sq))));
      sq = fmaf(b.x, b.x, fmaf(b.y, b.y, fmaf(b.z, b.z, fmaf(b.w, b.w, sq))));
      tf[mk] = cvt8(a, b);
    }
    sum += __shfl_xor(sum, 16); sum += __shfl_xor(sum, 32);
    sq  += __shfl_xor(sq, 16);  sq  += __shfl_xor(sq, 32);
    float mu = sum * (1.f/128.f);
    float rs = rsqrtf(sq * (1.f/128.f) - mu*mu + 1e-5f);
    f32x4 D = {0.f, 0.f, 0.f, 0.f};
    #pragma unroll
    for (int mk = 0; mk < 4; mk++)
      D = MFMA16(af[mk], tf[mk], D);
    #pragma unroll
    for (int r = 0; r < 4; r++)
      bounce[g*4 + r][w*16 + jl] = f2bf(rs*(D[r] - mu*c1r[r]) + c2r[r]);
    __syncthreads();
    {
      int h = tid >> 5, part = tid & 31;
      ushort4 vv = *(const ushort4*)(&bounce[h][part*4]);
      *(ushort4*)(bias + ((size_t)h << 20) + (size_t)(u >> 3)*1024 + (u & 7)*128 + part*4) = vv;
    }
    __syncthreads();
  }
}

// ---------------- qkvg projection GEMM: f32 inputs, convert in-register ----------------
// wave tile 32x64; block 64x128. B matrix selected by bx>>3 (wq|wk|wv|wg).
__global__ __launch_bounds__(256) void gemm_qkvg(
    const float* __restrict__ s, const float* __restrict__ wq,
    const float* __restrict__ wk, const float* __restrict__ wv,
    const float* __restrict__ wg, const float* __restrict__ bq,
    unsigned short* __restrict__ qb, unsigned short* __restrict__ kb,
    unsigned short* __restrict__ vT, unsigned short* __restrict__ gb)
{
  int lane = threadIdx.x & 63;
  int w = threadIdx.x >> 6;
  int lr = lane & 15, lg = lane >> 4;
  int row0 = blockIdx.y * 64 + (w & 1) * 32;
  int bx = blockIdx.x;
  const float* Bm = (bx < 8) ? wq : (bx < 16) ? wk : (bx < 24) ? wv : wg;
  int colL = (bx & 7) * 128 + (w >> 1) * 64;
  int colG = bx * 128 + (w >> 1) * 64;
  f32x4 acc[2][4] = {};
  for (int kk = 0; kk < 1024; kk += 32) {
    bf16x8 af[2], bfr[4];
    #pragma unroll
    for (int t = 0; t < 2; t++) {
      const float* p = s + (size_t)(row0 + t*16 + lr)*1024 + kk + lg*8;
      af[t] = cvt8(*(const float4*)p, *(const float4*)(p + 4));
    }
    #pragma unroll
    for (int t = 0; t < 4; t++) {
      const float* p = Bm + (size_t)(colL + t*16 + lr)*1024 + kk + lg*8;
      bfr[t] = cvt8(*(const float4*)p, *(const float4*)(p + 4));
    }
    #pragma unroll
    for (int a = 0; a < 2; a++)
      #pragma unroll
      for (int b = 0; b < 4; b++)
        acc[a][b] = MFMA16(af[a], bfr[b], acc[a][b]);
  }
  #pragma unroll
  for (int a = 0; a < 2; a++)
    #pragma unroll
    for (int b = 0; b < 4; b++)
      #pragma unroll
      for (int r = 0; r < 4; r++) {
        int m = row0 + a*16 + lg*4 + r;
        int n = colG + b*16 + lr;
        float v = acc[a][b][r];
        if (n < 1024)      { v = (v + bq[n]) * 0.125f; qb[(size_t)m*1024 + n] = f2bf(v); }
        else if (n < 2048) { kb[(size_t)m*1024 + (n-1024)] = f2bf(v); }
        else if (n < 3072) { vT[(size_t)(n-2048)*1024 + m] = f2bf(v); }
        else               { float sg = 1.f / (1.f + __expf(-v)); gb[(size_t)m*1024 + (n-3072)] = f2bf(sg); }
      }
}

// ---------------- output GEMM: (o*g) @ wo^T, A bf16, B f32-direct ----------------
__global__ __launch_bounds__(256) void gemm_out(
    const unsigned short* __restrict__ A, const float* __restrict__ wo,
    float* __restrict__ outF)
{
  int lane = threadIdx.x & 63;
  int w = threadIdx.x >> 6;
  int lr = lane & 15, lg = lane >> 4;
  int row0 = blockIdx.y * 64 + (w & 1) * 32;
  int col0 = blockIdx.x * 128 + (w >> 1) * 64;
  f32x4 acc[2][4] = {};
  for (int kk = 0; kk < 1024; kk += 32) {
    bf16x8 af[2], bfr[4];
    #pragma unroll
    for (int t = 0; t < 2; t++)
      af[t] = *(const bf16x8*)(A + (size_t)(row0 + t*16 + lr)*1024 + kk + lg*8);
    #pragma unroll
    for (int t = 0; t < 4; t++) {
      const float* p = wo + (size_t)(col0 + t*16 + lr)*1024 + kk + lg*8;
      bfr[t] = cvt8(*(const float4*)p, *(const float4*)(p + 4));
    }
    #pragma unroll
    for (int a = 0; a < 2; a++)
      #pragma unroll
      for (int b = 0; b < 4; b++)
        acc[a][b] = MFMA16(af[a], bfr[b], acc[a][b]);
  }
  #pragma unroll
  for (int a = 0; a < 2; a++)
    #pragma unroll
    for (int b = 0; b < 4; b++)
      #pragma unroll
      for (int r = 0; r < 4; r++) {
        int m = row0 + a*16 + lg*4 + r;
        int n = col0 + b*16 + lr;
        outF[(size_t)m * 1024 + n] = acc[a][b][r];
      }
}

// ---------------- attention: swapped-QK^T flash, 4-way j-split, bf16 bias ----------------
__global__ __launch_bounds__(256) void attn_kernel(
    const unsigned short* __restrict__ qb, const unsigned short* __restrict__ kb,
    const unsigned short* __restrict__ vT, const unsigned short* __restrict__ bias,
    float* __restrict__ op, float* __restrict__ ml, float* __restrict__ ll)
{
  __shared__ unsigned short P[4][1024];   // per-wave 16q x 64j, XOR-swizzled 8-short blocks
  int lane = threadIdx.x & 63;
  int s = threadIdx.x >> 6;
  int jl = lane & 15, g = lane >> 4;
  int q0 = blockIdx.x * 16;
  int h = blockIdx.y;
  unsigned short* Pw = P[s];

  bf16x8 aq[2];
  #pragma unroll
  for (int kh = 0; kh < 2; kh++)
    aq[kh] = *(const bf16x8*)(qb + (size_t)(q0 + jl)*1024 + h*64 + kh*32 + g*8);

  f32x4 od[4] = {};
  float m = -1e30f, ss = 0.f;
  const unsigned short* bp = bias + ((size_t)h << 20);

  for (int jt = s*256; jt < s*256 + 256; jt += 64) {
    f32x4 sc[4] = {};
    #pragma unroll
    for (int jb = 0; jb < 4; jb++)
      #pragma unroll
      for (int kh = 0; kh < 2; kh++) {
        bf16x8 bk = *(const bf16x8*)(kb + (size_t)(jt + jb*16 + jl)*1024 + h*64 + kh*32 + g*8);
        sc[jb] = MFMA16(bk, aq[kh], sc[jb]);   // swapped: rows=j, cols=q
      }
    #pragma unroll
    for (int jb = 0; jb < 4; jb++) {
      ushort4 bl = *(const ushort4*)(bp + (size_t)(q0 + jl)*1024 + jt + jb*16 + g*4);
      sc[jb][0] += bf2f(bl.x); sc[jb][1] += bf2f(bl.y);
      sc[jb][2] += bf2f(bl.z); sc[jb][3] += bf2f(bl.w);
    }

    float mx = -1e30f;
    #pragma unroll
    for (int jb = 0; jb < 4; jb++)
      #pragma unroll
      for (int r = 0; r < 4; r++) mx = fmaxf(mx, sc[jb][r]);
    mx = fmaxf(mx, __shfl_xor(mx, 16));
    mx = fmaxf(mx, __shfl_xor(mx, 32));
    float mn = fmaxf(m, mx);
    float a = __expf(m - mn);
    m = mn;
    float rsum = 0.f;
    #pragma unroll
    for (int jb = 0; jb < 4; jb++) {
      short4 pk;
      float p0 = __expf(sc[jb][0] - mn); rsum += p0; pk.x = (short)f2bf(p0);
      float p1 = __expf(sc[jb][1] - mn); rsum += p1; pk.y = (short)f2bf(p1);
      float p2 = __expf(sc[jb][2] - mn); rsum += p2; pk.z = (short)f2bf(p2);
      float p3 = __expf(sc[jb][3] - mn); rsum += p3; pk.w = (short)f2bf(p3);
      int b = jb*2 + (g >> 1);
      int bpz = b ^ (jl & 7);
      *(short4*)(Pw + jl*64 + bpz*8 + (g & 1)*4) = pk;
    }
    ss = ss * a + rsum;   // per-lane quarter-partial (reduced over g at the end)

    float albc[4];
    #pragma unroll
    for (int r = 0; r < 4; r++) albc[r] = __shfl(a, g*4 + r);
    #pragma unroll
    for (int db = 0; db < 4; db++)
      #pragma unroll
      for (int r = 0; r < 4; r++) od[db][r] *= albc[r];

    #pragma unroll
    for (int jh = 0; jh < 2; jh++) {
      int b = jh*4 + g;
      int bpz = b ^ (jl & 7);
      bf16x8 ap = *(const bf16x8*)(Pw + jl*64 + bpz*8);
      #pragma unroll
      for (int db = 0; db < 4; db++) {
        bf16x8 bv = *(const bf16x8*)(vT + (size_t)(h*64 + db*16 + jl)*1024 + jt + jh*32 + g*8);
        od[db] = MFMA16(ap, bv, od[db]);
      }
    }
  }

  // ss holds this lane-group's quarter; reduce across the 4 groups (same jl)
  ss += __shfl_xor(ss, 16);
  ss += __shfl_xor(ss, 32);

  size_t base = ((size_t)(s*16 + h) * 1024);
  #pragma unroll
  for (int db = 0; db < 4; db++)
    #pragma unroll
    for (int r = 0; r < 4; r++) {
      int q = q0 + g*4 + r;
      op[(base + q)*64 + db*16 + jl] = od[db][r];
    }
  if (g == 0) {
    ml[base + q0 + jl] = m;
    ll[base + q0 + jl] = ss;
  }
}

// ---------------- combine: merge 4 j-split partials, gate, bf16 ----------------
__global__ __launch_bounds__(256) void combine_kernel(
    const float* __restrict__ op, const float* __restrict__ ml,
    const float* __restrict__ ll, const unsigned short* __restrict__ gb,
    unsigned short* __restrict__ og)
{
  int t = blockIdx.x * 256 + threadIdx.x;   // over 16h * 1024q * 16d4
  int d4 = t & 15;
  int q = (t >> 4) & 1023;
  int h = t >> 14;

  float mv[4], lv[4];
  float mstar = -1e30f;
  #pragma unroll
  for (int s = 0; s < 4; s++) {
    mv[s] = ml[(size_t)(s*16 + h)*1024 + q];
    lv[s] = ll[(size_t)(s*16 + h)*1024 + q];
    mstar = fmaxf(mstar, mv[s]);
  }
  float lsum = 0.f;
  float ws[4];
  #pragma unroll
  for (int s = 0; s < 4; s++) {
    ws[s] = __expf(mv[s] - mstar);
    lsum = fmaf(ws[s], lv[s], lsum);
  }
  float inv = 1.f / lsum;

  float4 o = {0.f, 0.f, 0.f, 0.f};
  #pragma unroll
  for (int s = 0; s < 4; s++) {
    float4 p = *(const float4*)(op + ((size_t)(s*16 + h)*1024 + q)*64 + d4*4);
    o.x = fmaf(ws[s], p.x, o.x); o.y = fmaf(ws[s], p.y, o.y);
    o.z = fmaf(ws[s], p.z, o.z); o.w = fmaf(ws[s], p.w, o.w);
  }
  ushort4 gv = *(const ushort4*)(gb + (size_t)q*1024 + h*64 + d4*4);
  ushort4 r;
  r.x = f2bf(o.x * inv * bf2f(gv.x));
  r.y = f2bf(o.y * inv * bf2f(gv.y));
  r.z = f2bf(o.z * inv * bf2f(gv.z));
  r.w = f2bf(o.w * inv * bf2f(gv.w));
  *(ushort4*)(og + (size_t)q*1024 + h*64 + d4*4) = r;
}

extern "C" void kernel_launch(void* const* d_in, const int* in_sizes, int n_in,
                              void* d_out, int out_size, void* d_ws, size_t ws_size,
                              hipStream_t stream) {
  const float* s   = (const float*)d_in[0];
  const float* z   = (const float*)d_in[1];
  const float* wq  = (const float*)d_in[2];
  const float* bq  = (const float*)d_in[3];
  const float* wk  = (const float*)d_in[4];
  const float* wv  = (const float*)d_in[5];
  const float* wg  = (const float*)d_in[6];
  const float* znw = (const float*)d_in[7];
  const float* znb = (const float*)d_in[8];
  const float* wz  = (const float*)d_in[9];
  const float* wo  = (const float*)d_in[10];
  float* out = (float*)d_out;

  char* ws = (char*)d_ws;
  unsigned short* biasb = (unsigned short*)ws;                         // 32 MB (bf16)
  unsigned short* qbuf  = (unsigned short*)(ws + ((size_t)64 << 20));  // 2 MB
  unsigned short* kbuf  = (unsigned short*)(ws + ((size_t)66 << 20));  // 2 MB
  unsigned short* vTb   = (unsigned short*)(ws + ((size_t)68 << 20));  // 2 MB
  unsigned short* gbuf  = (unsigned short*)(ws + ((size_t)70 << 20));  // 2 MB
  unsigned short* ogb   = (unsigned short*)(ws + ((size_t)72 << 20));  // 2 MB
  unsigned short* wzp   = (unsigned short*)(ws + ((size_t)86 << 20));  // 4 KB
  float*          c12   = (float*)(ws + ((size_t)86 << 20) + 4096);    // 128 B
  float*          opart = (float*)(ws + ((size_t)96 << 20));           // 16 MB
  float*          mlb   = (float*)(ws + ((size_t)112 << 20));          // 256 KB
  float*          llb   = (float*)(ws + ((size_t)113 << 20));          // 256 KB

  wzprep_kernel<<<1, 256, 0, stream>>>(wz, znw, znb, wzp, c12);
  gemm_qkvg<<<dim3(32, 16), 256, 0, stream>>>(s, wq, wk, wv, wg, bq,
                                              qbuf, kbuf, vTb, gbuf);
  bias_stream<<<256, 512, 0, stream>>>(z, wzp, c12, biasb);
  attn_kernel<<<dim3(64, 16), 256, 0, stream>>>(qbuf, kbuf, vTb, biasb, opart, mlb, llb);
  combine_kernel<<<1024, 256, 0, stream>>>(opart, mlb, llb, gbuf, ogb);
  gemm_out<<<dim3(8, 16), 256, 0, stream>>>(ogb, wo, out);
}

// Round 8
// 269.531 us; speedup vs baseline: 1.1319x; 1.1319x over previous
//
#include <hip/hip_runtime.h>

typedef __attribute__((ext_vector_type(8))) short bf16x8;
typedef __attribute__((ext_vector_type(4))) float f32x4;

#define MFMA16(a,b,c) __builtin_amdgcn_mfma_f32_16x16x32_bf16(a,b,c,0,0,0)

__device__ __forceinline__ unsigned short f2bf(float f){
  unsigned int u = __float_as_uint(f);
  unsigned int r = (u + 0x7fffu + ((u >> 16) & 1u)) >> 16;
  return (unsigned short)r;
}
__device__ __forceinline__ float bf2f(unsigned short u){
  return __uint_as_float(((unsigned int)u) << 16);
}
__device__ __forceinline__ bf16x8 cvt8(float4 a, float4 b){
  bf16x8 t;
  t[0] = (short)f2bf(a.x); t[1] = (short)f2bf(a.y);
  t[2] = (short)f2bf(a.z); t[3] = (short)f2bf(a.w);
  t[4] = (short)f2bf(b.x); t[5] = (short)f2bf(b.y);
  t[6] = (short)f2bf(b.z); t[7] = (short)f2bf(b.w);
  return t;
}

// ---------------- prep: f32 -> bf16 conversions (+ embedded wz prep) ----------------
__global__ __launch_bounds__(256) void prep_kernel(
    const float* __restrict__ s, const float* __restrict__ wq,
    const float* __restrict__ wk, const float* __restrict__ wv,
    const float* __restrict__ wg, const float* __restrict__ wo,
    const float* __restrict__ wz, const float* __restrict__ znw,
    const float* __restrict__ znb,
    unsigned short* __restrict__ sb, unsigned short* __restrict__ Wp,
    unsigned short* __restrict__ wob,
    unsigned short* __restrict__ wzp, float* __restrict__ c12)
{
  __shared__ float r1[256], r2[256];
  if (blockIdx.x == 6144) {
    int t = threadIdx.x; int h = t >> 4; int k0 = (t & 15) * 8;
    float p1 = 0.f, p2 = 0.f;
    for (int e = 0; e < 8; e++) {
      float wvv = wz[h*128 + k0 + e];
      float w = znw[k0 + e], b = znb[k0 + e];
      wzp[h*128 + k0 + e] = f2bf(wvv * w);
      p1 += wvv * w; p2 += wvv * b;
    }
    r1[t] = p1; r2[t] = p2;
    __syncthreads();
    if ((t & 15) == 0) {
      float s1 = 0.f, s2 = 0.f;
      for (int i = 0; i < 16; i++) { s1 += r1[t + i]; s2 += r2[t + i]; }
      c12[2*h] = s1; c12[2*h + 1] = s2;
    }
    return;
  }
  const size_t M1 = 1u << 20;
  size_t base = ((size_t)blockIdx.x * 256 + threadIdx.x) * 4;
  const float* src; unsigned short* dst; size_t off;
  if (base < M1) { src = s; dst = sb; off = base; }
  else if (base < 5*M1) {
    size_t r = base - M1; int wsel = (int)(r >> 20);
    const float* wsrc0 = (wsel == 0) ? wq : (wsel == 1) ? wk : (wsel == 2) ? wv : wg;
    src = wsrc0; dst = Wp + ((size_t)wsel << 20); off = r & (M1 - 1);
  } else { src = wo; dst = wob; off = base - 5*M1; }
  float4 v = *(const float4*)(src + off);
  ushort4 o4;
  o4.x = f2bf(v.x); o4.y = f2bf(v.y); o4.z = f2bf(v.z); o4.w = f2bf(v.w);
  *(ushort4*)(dst + off) = o4;
}

// ---------------- bias_stream: bias[h][i][j] = LN(z[i,j,:]) . wz[h,:]  (bf16 out) ----------------
// RACE-FREE BY CONSTRUCTION: no s_barrier / __syncthreads anywhere; every LDS
// region (zbuf slice, bounce slice) is WAVE-PRIVATE; sync is per-wave counted
// vmcnt + lgkmcnt only. Each wave: 32 steps, each step = one (i, 16-j) unit:
//   stage next unit's 16 z-rows (8 KB) via global_load_lds (double-buffered)
//   vmcnt(8)  -> current buffer resident, next 8 glls stay in flight
//   LDS->reg (XOR-swizzled), LN stats, MFMA vs wz', transpose via private
//   bounce (lgkmcnt(0)+sched_barrier, same-wave), coalesced ushort4 stores.
__global__ __launch_bounds__(512) void bias_stream(
    const float* __restrict__ z, const unsigned short* __restrict__ wzp,
    const float* __restrict__ c12, unsigned short* __restrict__ bias)
{
  __shared__ __align__(1024) char zbuf[2 * 65536];          // 2 bufs x 8 waves x 8 KB
  __shared__ __align__(16) unsigned short bounce[8][16][20]; // per-wave 16h x 16j (+pad)
  int tid = threadIdx.x;
  int w = tid >> 6, lane = tid & 63;
  int jl = lane & 15, g = lane >> 4;
  int half = lane >> 5, lane31 = lane & 31;

  bf16x8 af[4];
  #pragma unroll
  for (int mk = 0; mk < 4; mk++)
    af[mk] = *(const bf16x8*)(wzp + jl*128 + mk*32 + g*8);
  float c1r[4], c2r[4];
  #pragma unroll
  for (int r = 0; r < 4; r++) {
    c1r[r] = c12[2*(g*4 + r)];
    c2r[r] = c12[2*(g*4 + r) + 1];
  }
  // readback lane role: head hp, j-quad gp
  int hp = lane & 15, gp = lane >> 4;

  const int nsteps = 32;
  int W = blockIdx.x * 8 + w;          // global wave id, 0..2047
  int u0 = W * nsteps;                 // units: u = i*64 + j16

  auto stage = [&](int u, int buf) {
    int i = u >> 6, j16 = u & 63;
    const char* gw = (const char*)z + (((size_t)i*1024 + j16*16) << 9);
    char* lb = zbuf + buf*65536 + w*8192;
    #pragma unroll
    for (int c = 0; c < 8; c++) {
      int row = c*2 + half;
      unsigned pin = (unsigned)(lane31*16) ^ (unsigned)((row & 7) << 4);
      __builtin_amdgcn_global_load_lds(
          (const unsigned int*)(gw + (size_t)row*512 + pin),
          (unsigned int*)(lb + c*1024), 16, 0, 0);
    }
  };

  stage(u0, 0);
  #pragma unroll 1
  for (int step = 0; step < nsteps; ++step) {
    int u = u0 + step;
    int buf = step & 1;
    if (step + 1 < nsteps) {
      stage(u + 1, buf ^ 1);
      // per-wave outstanding: [cur 8 glls (oldest)][prev store][next 8 glls]
      // vmcnt(8): cur buffer + prev store complete; next 8 stay in flight.
      asm volatile("s_waitcnt vmcnt(8)" ::: "memory");
    } else {
      asm volatile("s_waitcnt vmcnt(1)" ::: "memory");
    }
    __builtin_amdgcn_sched_barrier(0);

    const char* wb = zbuf + buf*65536 + w*8192;
    unsigned key = (unsigned)((jl & 7) << 4);
    float sum = 0.f, sq = 0.f;
    bf16x8 tf[4];
    #pragma unroll
    for (int mk = 0; mk < 4; mk++) {
      unsigned x = (unsigned)(mk*128 + g*32);
      float4 a = *(const float4*)(wb + jl*512 + (x ^ key));
      float4 b = *(const float4*)(wb + jl*512 + ((x + 16) ^ key));
      sum += a.x + a.y + a.z + a.w + b.x + b.y + b.z + b.w;
      sq = fmaf(a.x, a.x, fmaf(a.y, a.y, fmaf(a.z, a.z, fmaf(a.w, a.w, sq))));
      sq = fmaf(b.x, b.x, fmaf(b.y, b.y, fmaf(b.z, b.z, fmaf(b.w, b.w, sq))));
      tf[mk] = cvt8(a, b);
    }
    sum += __shfl_xor(sum, 16); sum += __shfl_xor(sum, 32);
    sq  += __shfl_xor(sq, 16);  sq  += __shfl_xor(sq, 32);
    float mu = sum * (1.f/128.f);
    float rs = rsqrtf(sq * (1.f/128.f) - mu*mu + 1e-5f);
    f32x4 D = {0.f, 0.f, 0.f, 0.f};
    #pragma unroll
    for (int mk = 0; mk < 4; mk++)
      D = MFMA16(af[mk], tf[mk], D);

    // transpose through WAVE-PRIVATE bounce slice (same-wave DS ordering only)
    #pragma unroll
    for (int r = 0; r < 4; r++)
      bounce[w][g*4 + r][jl] = f2bf(rs*(D[r] - mu*c1r[r]) + c2r[r]);
    asm volatile("s_waitcnt lgkmcnt(0)" ::: "memory");
    __builtin_amdgcn_sched_barrier(0);
    {
      int i = u >> 6, j16 = u & 63;
      ushort4 vv = *(const ushort4*)(&bounce[w][hp][gp*4]);
      *(ushort4*)(bias + ((size_t)hp << 20) + (size_t)i*1024 + j16*16 + gp*4) = vv;
    }
    asm volatile("s_waitcnt lgkmcnt(0)" ::: "memory");   // readback done before next
    __builtin_amdgcn_sched_barrier(0);                   // step rewrites bounce
  }
}

// ---------------- bf16 GEMM: C[M][N] = A[M][K] * B[N][K]^T ----------------
template<int MODE>
__global__ __launch_bounds__(256) void gemm_bf16(
    const unsigned short* __restrict__ A, const unsigned short* __restrict__ Bm,
    int M, int N, int K,
    const float* __restrict__ bq,
    unsigned short* __restrict__ qb, unsigned short* __restrict__ kb,
    unsigned short* __restrict__ vT, unsigned short* __restrict__ gb,
    float* __restrict__ outF)
{
  int lane = threadIdx.x & 63;
  int w = threadIdx.x >> 6;
  int lr = lane & 15, lg = lane >> 4;
  int row0 = blockIdx.y * 64 + (w & 1) * 32;
  int col0 = blockIdx.x * 128 + (w >> 1) * 64;
  f32x4 acc[2][4] = {};
  for (int kk = 0; kk < K; kk += 32) {
    bf16x8 af[2], bfr[4];
    #pragma unroll
    for (int t = 0; t < 2; t++)
      af[t] = *(const bf16x8*)(A + (size_t)(row0 + t*16 + lr) * K + kk + lg*8);
    #pragma unroll
    for (int t = 0; t < 4; t++)
      bfr[t] = *(const bf16x8*)(Bm + (size_t)(col0 + t*16 + lr) * K + kk + lg*8);
    #pragma unroll
    for (int a = 0; a < 2; a++)
      #pragma unroll
      for (int b = 0; b < 4; b++)
        acc[a][b] = MFMA16(af[a], bfr[b], acc[a][b]);
  }
  #pragma unroll
  for (int a = 0; a < 2; a++)
    #pragma unroll
    for (int b = 0; b < 4; b++)
      #pragma unroll
      for (int r = 0; r < 4; r++) {
        int m = row0 + a*16 + lg*4 + r;
        int n = col0 + b*16 + lr;
        float v = acc[a][b][r];
        if (MODE == 0) {
          if (n < 1024)      { v = (v + bq[n]) * 0.125f; qb[(size_t)m*1024 + n] = f2bf(v); }
          else if (n < 2048) { kb[(size_t)m*1024 + (n-1024)] = f2bf(v); }
          else if (n < 3072) { vT[(size_t)(n-2048)*1024 + m] = f2bf(v); }
          else               { float sg = 1.f / (1.f + __expf(-v)); gb[(size_t)m*1024 + (n-3072)] = f2bf(sg); }
        } else {
          outF[(size_t)m * N + n] = v;
        }
      }
}

// ---------------- attention: swapped-QK^T flash, 4-way j-split, bf16 bias ----------------
__global__ __launch_bounds__(256) void attn_kernel(
    const unsigned short* __restrict__ qb, const unsigned short* __restrict__ kb,
    const unsigned short* __restrict__ vT, const unsigned short* __restrict__ bias,
    float* __restrict__ op, float* __restrict__ ml, float* __restrict__ ll)
{
  __shared__ unsigned short P[4][1024];
  int lane = threadIdx.x & 63;
  int s = threadIdx.x >> 6;
  int jl = lane & 15, g = lane >> 4;
  int q0 = blockIdx.x * 16;
  int h = blockIdx.y;
  unsigned short* Pw = P[s];

  bf16x8 aq[2];
  #pragma unroll
  for (int kh = 0; kh < 2; kh++)
    aq[kh] = *(const bf16x8*)(qb + (size_t)(q0 + jl)*1024 + h*64 + kh*32 + g*8);

  f32x4 od[4] = {};
  float m = -1e30f, ss = 0.f;
  const unsigned short* bp = bias + ((size_t)h << 20);

  for (int jt = s*256; jt < s*256 + 256; jt += 64) {
    f32x4 sc[4] = {};
    #pragma unroll
    for (int jb = 0; jb < 4; jb++)
      #pragma unroll
      for (int kh = 0; kh < 2; kh++) {
        bf16x8 bk = *(const bf16x8*)(kb + (size_t)(jt + jb*16 + jl)*1024 + h*64 + kh*32 + g*8);
        sc[jb] = MFMA16(bk, aq[kh], sc[jb]);
      }
    #pragma unroll
    for (int jb = 0; jb < 4; jb++) {
      ushort4 bl = *(const ushort4*)(bp + (size_t)(q0 + jl)*1024 + jt + jb*16 + g*4);
      sc[jb][0] += bf2f(bl.x); sc[jb][1] += bf2f(bl.y);
      sc[jb][2] += bf2f(bl.z); sc[jb][3] += bf2f(bl.w);
    }

    float mx = -1e30f;
    #pragma unroll
    for (int jb = 0; jb < 4; jb++)
      #pragma unroll
      for (int r = 0; r < 4; r++) mx = fmaxf(mx, sc[jb][r]);
    mx = fmaxf(mx, __shfl_xor(mx, 16));
    mx = fmaxf(mx, __shfl_xor(mx, 32));
    float mn = fmaxf(m, mx);
    float a = __expf(m - mn);
    m = mn;
    float rsum = 0.f;
    #pragma unroll
    for (int jb = 0; jb < 4; jb++) {
      short4 pk;
      float p0 = __expf(sc[jb][0] - mn); rsum += p0; pk.x = (short)f2bf(p0);
      float p1 = __expf(sc[jb][1] - mn); rsum += p1; pk.y = (short)f2bf(p1);
      float p2 = __expf(sc[jb][2] - mn); rsum += p2; pk.z = (short)f2bf(p2);
      float p3 = __expf(sc[jb][3] - mn); rsum += p3; pk.w = (short)f2bf(p3);
      int b = jb*2 + (g >> 1);
      int bpz = b ^ (jl & 7);
      *(short4*)(Pw + jl*64 + bpz*8 + (g & 1)*4) = pk;
    }
    ss = ss * a + rsum;

    float albc[4];
    #pragma unroll
    for (int r = 0; r < 4; r++) albc[r] = __shfl(a, g*4 + r);
    #pragma unroll
    for (int db = 0; db < 4; db++)
      #pragma unroll
      for (int r = 0; r < 4; r++) od[db][r] *= albc[r];

    #pragma unroll
    for (int jh = 0; jh < 2; jh++) {
      int b = jh*4 + g;
      int bpz = b ^ (jl & 7);
      bf16x8 ap = *(const bf16x8*)(Pw + jl*64 + bpz*8);
      #pragma unroll
      for (int db = 0; db < 4; db++) {
        bf16x8 bv = *(const bf16x8*)(vT + (size_t)(h*64 + db*16 + jl)*1024 + jt + jh*32 + g*8);
        od[db] = MFMA16(ap, bv, od[db]);
      }
    }
  }

  ss += __shfl_xor(ss, 16);
  ss += __shfl_xor(ss, 32);

  size_t base = ((size_t)(s*16 + h) * 1024);
  #pragma unroll
  for (int db = 0; db < 4; db++)
    #pragma unroll
    for (int r = 0; r < 4; r++) {
      int q = q0 + g*4 + r;
      op[(base + q)*64 + db*16 + jl] = od[db][r];
    }
  if (g == 0) {
    ml[base + q0 + jl] = m;
    ll[base + q0 + jl] = ss;
  }
}

// ---------------- combine: merge 4 j-split partials, gate, bf16 ----------------
__global__ __launch_bounds__(256) void combine_kernel(
    const float* __restrict__ op, const float* __restrict__ ml,
    const float* __restrict__ ll, const unsigned short* __restrict__ gb,
    unsigned short* __restrict__ og)
{
  int t = blockIdx.x * 256 + threadIdx.x;
  int d4 = t & 15;
  int q = (t >> 4) & 1023;
  int h = t >> 14;

  float mv[4], lv[4];
  float mstar = -1e30f;
  #pragma unroll
  for (int s = 0; s < 4; s++) {
    mv[s] = ml[(size_t)(s*16 + h)*1024 + q];
    lv[s] = ll[(size_t)(s*16 + h)*1024 + q];
    mstar = fmaxf(mstar, mv[s]);
  }
  float lsum = 0.f;
  float ws[4];
  #pragma unroll
  for (int s = 0; s < 4; s++) {
    ws[s] = __expf(mv[s] - mstar);
    lsum = fmaf(ws[s], lv[s], lsum);
  }
  float inv = 1.f / lsum;

  float4 o = {0.f, 0.f, 0.f, 0.f};
  #pragma unroll
  for (int s = 0; s < 4; s++) {
    float4 p = *(const float4*)(op + ((size_t)(s*16 + h)*1024 + q)*64 + d4*4);
    o.x = fmaf(ws[s], p.x, o.x); o.y = fmaf(ws[s], p.y, o.y);
    o.z = fmaf(ws[s], p.z, o.z); o.w = fmaf(ws[s], p.w, o.w);
  }
  ushort4 gv = *(const ushort4*)(gb + (size_t)q*1024 + h*64 + d4*4);
  ushort4 r;
  r.x = f2bf(o.x * inv * bf2f(gv.x));
  r.y = f2bf(o.y * inv * bf2f(gv.y));
  r.z = f2bf(o.z * inv * bf2f(gv.z));
  r.w = f2bf(o.w * inv * bf2f(gv.w));
  *(ushort4*)(og + (size_t)q*1024 + h*64 + d4*4) = r;
}

extern "C" void kernel_launch(void* const* d_in, const int* in_sizes, int n_in,
                              void* d_out, int out_size, void* d_ws, size_t ws_size,
                              hipStream_t stream) {
  const float* s   = (const float*)d_in[0];
  const float* z   = (const float*)d_in[1];
  const float* wq  = (const float*)d_in[2];
  const float* bq  = (const float*)d_in[3];
  const float* wk  = (const float*)d_in[4];
  const float* wv  = (const float*)d_in[5];
  const float* wg  = (const float*)d_in[6];
  const float* znw = (const float*)d_in[7];
  const float* znb = (const float*)d_in[8];
  const float* wz  = (const float*)d_in[9];
  const float* wo  = (const float*)d_in[10];
  float* out = (float*)d_out;

  char* ws = (char*)d_ws;
  unsigned short* biasb = (unsigned short*)ws;                         // 32 MB (bf16)
  unsigned short* qbuf  = (unsigned short*)(ws + ((size_t)64 << 20));  // 2 MB
  unsigned short* kbuf  = (unsigned short*)(ws + ((size_t)66 << 20));  // 2 MB
  unsigned short* vTb   = (unsigned short*)(ws + ((size_t)68 << 20));  // 2 MB
  unsigned short* gbuf  = (unsigned short*)(ws + ((size_t)70 << 20));  // 2 MB
  unsigned short* ogb   = (unsigned short*)(ws + ((size_t)72 << 20));  // 2 MB
  unsigned short* sb    = (unsigned short*)(ws + ((size_t)74 << 20));  // 2 MB
  unsigned short* Wp    = (unsigned short*)(ws + ((size_t)76 << 20));  // 8 MB
  unsigned short* wob   = (unsigned short*)(ws + ((size_t)84 << 20));  // 2 MB
  unsigned short* wzp   = (unsigned short*)(ws + ((size_t)86 << 20));  // 4 KB
  float*          c12   = (float*)(ws + ((size_t)86 << 20) + 4096);    // 128 B
  float*          opart = (float*)(ws + ((size_t)96 << 20));           // 16 MB
  float*          mlb   = (float*)(ws + ((size_t)112 << 20));          // 256 KB
  float*          llb   = (float*)(ws + ((size_t)113 << 20));          // 256 KB

  prep_kernel<<<6145, 256, 0, stream>>>(s, wq, wk, wv, wg, wo, wz, znw, znb,
                                        sb, Wp, wob, wzp, c12);
  gemm_bf16<0><<<dim3(32, 16), 256, 0, stream>>>(sb, Wp, 1024, 4096, 1024, bq,
                                                 qbuf, kbuf, vTb, gbuf, nullptr);
  bias_stream<<<256, 512, 0, stream>>>(z, wzp, c12, biasb);
  attn_kernel<<<dim3(64, 16), 256, 0, stream>>>(qbuf, kbuf, vTb, biasb, opart, mlb, llb);
  combine_kernel<<<1024, 256, 0, stream>>>(opart, mlb, llb, gbuf, ogb);
  gemm_bf16<1><<<dim3(8, 16), 256, 0, stream>>>(ogb, wob, 1024, 1024, 1024, nullptr,
                                                nullptr, nullptr, nullptr, nullptr, out);
}

// Round 9
// 255.324 us; speedup vs baseline: 1.1949x; 1.0556x over previous
//
#include <hip/hip_runtime.h>

typedef __attribute__((ext_vector_type(8))) short bf16x8;
typedef __attribute__((ext_vector_type(4))) float f32x4;

#define MFMA16(a,b,c) __builtin_amdgcn_mfma_f32_16x16x32_bf16(a,b,c,0,0,0)

__device__ __forceinline__ unsigned short f2bf(float f){
  unsigned int u = __float_as_uint(f);
  unsigned int r = (u + 0x7fffu + ((u >> 16) & 1u)) >> 16;
  return (unsigned short)r;
}
__device__ __forceinline__ float bf2f(unsigned short u){
  return __uint_as_float(((unsigned int)u) << 16);
}
__device__ __forceinline__ bf16x8 cvt8(float4 a, float4 b){
  bf16x8 t;
  t[0] = (short)f2bf(a.x); t[1] = (short)f2bf(a.y);
  t[2] = (short)f2bf(a.z); t[3] = (short)f2bf(a.w);
  t[4] = (short)f2bf(b.x); t[5] = (short)f2bf(b.y);
  t[6] = (short)f2bf(b.z); t[7] = (short)f2bf(b.w);
  return t;
}

// ---------------- prep: f32 -> bf16 conversions (+ embedded wz prep) ----------------
__global__ __launch_bounds__(256) void prep_kernel(
    const float* __restrict__ s, const float* __restrict__ wq,
    const float* __restrict__ wk, const float* __restrict__ wv,
    const float* __restrict__ wg, const float* __restrict__ wo,
    const float* __restrict__ wz, const float* __restrict__ znw,
    const float* __restrict__ znb,
    unsigned short* __restrict__ sb, unsigned short* __restrict__ Wp,
    unsigned short* __restrict__ wob,
    unsigned short* __restrict__ wzp, float* __restrict__ c12)
{
  __shared__ float r1[256], r2[256];
  if (blockIdx.x == 6144) {
    int t = threadIdx.x; int h = t >> 4; int k0 = (t & 15) * 8;
    float p1 = 0.f, p2 = 0.f;
    for (int e = 0; e < 8; e++) {
      float wvv = wz[h*128 + k0 + e];
      float w = znw[k0 + e], b = znb[k0 + e];
      wzp[h*128 + k0 + e] = f2bf(wvv * w);
      p1 += wvv * w; p2 += wvv * b;
    }
    r1[t] = p1; r2[t] = p2;
    __syncthreads();
    if ((t & 15) == 0) {
      float s1 = 0.f, s2 = 0.f;
      for (int i = 0; i < 16; i++) { s1 += r1[t + i]; s2 += r2[t + i]; }
      c12[2*h] = s1; c12[2*h + 1] = s2;
    }
    return;
  }
  const size_t M1 = 1u << 20;
  size_t base = ((size_t)blockIdx.x * 256 + threadIdx.x) * 4;
  const float* src; unsigned short* dst; size_t off;
  if (base < M1) { src = s; dst = sb; off = base; }
  else if (base < 5*M1) {
    size_t r = base - M1; int wsel = (int)(r >> 20);
    const float* wsrc0 = (wsel == 0) ? wq : (wsel == 1) ? wk : (wsel == 2) ? wv : wg;
    src = wsrc0; dst = Wp + ((size_t)wsel << 20); off = r & (M1 - 1);
  } else { src = wo; dst = wob; off = base - 5*M1; }
  float4 v = *(const float4*)(src + off);
  ushort4 o4;
  o4.x = f2bf(v.x); o4.y = f2bf(v.y); o4.z = f2bf(v.z); o4.w = f2bf(v.w);
  *(ushort4*)(dst + off) = o4;
}

// ---------------- fused bias-stream + qkvg GEMM (role-split by blockIdx) --------------
// blocks [0,512): bias role. Register-staged z streaming, NO barriers, NO manual
//   waitcnt for loads (compiler inserts vmcnt for reg deps); per-wave 8 KB
//   prefetch depth -> ~64 KB/CU in flight. Wave-private LDS bounce for the
//   16x16 transpose (same-wave lgkmcnt only — R8-proven pattern).
// blocks [512,1024): qkvg projection GEMM (R5-proven body).
// 4 blocks/CU co-resident (union LDS ~2.6 KB) -> GEMM hides under z-stream.
__global__ __launch_bounds__(256) void bias_gemm(
    const float* __restrict__ z, const unsigned short* __restrict__ wzp,
    const float* __restrict__ c12, unsigned short* __restrict__ bias,
    const unsigned short* __restrict__ sb, const unsigned short* __restrict__ Wp,
    const float* __restrict__ bq,
    unsigned short* __restrict__ qb, unsigned short* __restrict__ kb,
    unsigned short* __restrict__ vT, unsigned short* __restrict__ gb)
{
  __shared__ __align__(16) unsigned short bounce[4][16][20];
  int tid = threadIdx.x;
  int w = tid >> 6, lane = tid & 63;
  int jl = lane & 15, g = lane >> 4;

  if (blockIdx.x < 512) {
    // ---------------- bias role ----------------
    bf16x8 af[4];
    #pragma unroll
    for (int mk = 0; mk < 4; mk++)
      af[mk] = *(const bf16x8*)(wzp + jl*128 + mk*32 + g*8);
    float c1r[4], c2r[4];
    #pragma unroll
    for (int r = 0; r < 4; r++) {
      c1r[r] = c12[2*(g*4 + r)];
      c2r[r] = c12[2*(g*4 + r) + 1];
    }

    int W = blockIdx.x * 4 + w;      // 0..2047
    int u0 = W * 32;                 // unit u = i*64 + j16 (16 j's each)

    float4 A0[8], A1[8];

    auto loadu = [&](int u, float4 (&A)[8]) {
      int i = u >> 6, j16 = u & 63;
      const float* p = z + ((size_t)i*1024 + j16*16 + jl)*128 + g*8;
      #pragma unroll
      for (int mk = 0; mk < 4; mk++) {
        A[2*mk]   = *(const float4*)(p + mk*32);
        A[2*mk+1] = *(const float4*)(p + mk*32 + 4);
      }
    };
    auto proc = [&](int u, float4 (&A)[8]) {
      float sum = 0.f, sq = 0.f;
      #pragma unroll
      for (int t = 0; t < 8; t++) {
        float4 v = A[t];
        sum += v.x + v.y + v.z + v.w;
        sq = fmaf(v.x, v.x, fmaf(v.y, v.y, fmaf(v.z, v.z, fmaf(v.w, v.w, sq))));
      }
      sum += __shfl_xor(sum, 16); sum += __shfl_xor(sum, 32);
      sq  += __shfl_xor(sq, 16);  sq  += __shfl_xor(sq, 32);
      float mu = sum * (1.f/128.f);
      float rs = rsqrtf(sq * (1.f/128.f) - mu*mu + 1e-5f);
      f32x4 D = {0.f, 0.f, 0.f, 0.f};
      #pragma unroll
      for (int mk = 0; mk < 4; mk++)
        D = MFMA16(af[mk], cvt8(A[2*mk], A[2*mk+1]), D);
      #pragma unroll
      for (int r = 0; r < 4; r++)
        bounce[w][g*4 + r][jl] = f2bf(rs*(D[r] - mu*c1r[r]) + c2r[r]);
      asm volatile("s_waitcnt lgkmcnt(0)" ::: "memory");
      __builtin_amdgcn_sched_barrier(0);
      {
        int i = u >> 6, j16 = u & 63;
        ushort4 vv = *(const ushort4*)(&bounce[w][jl][g*4]);
        *(ushort4*)(bias + ((size_t)jl << 20) + (size_t)i*1024 + j16*16 + g*4) = vv;
      }
      asm volatile("s_waitcnt lgkmcnt(0)" ::: "memory");  // bounce reads done
      __builtin_amdgcn_sched_barrier(0);                  // before next rewrite
    };

    loadu(u0, A0);
    #pragma unroll 1
    for (int st = 0; st < 32; st += 2) {
      if (st + 1 < 32) loadu(u0 + st + 1, A1);
      proc(u0 + st, A0);
      if (st + 2 < 32) loadu(u0 + st + 2, A0);
      proc(u0 + st + 1, A1);
    }
  } else {
    // ---------------- qkvg GEMM role ----------------
    int bxx = blockIdx.x - 512;
    int bx = bxx & 31, by = bxx >> 5;
    int lr = jl, lg = g;
    int row0 = by * 64 + (w & 1) * 32;
    int col0 = bx * 128 + (w >> 1) * 64;
    f32x4 acc[2][4] = {};
    for (int kk = 0; kk < 1024; kk += 32) {
      bf16x8 afr[2], bfr[4];
      #pragma unroll
      for (int t = 0; t < 2; t++)
        afr[t] = *(const bf16x8*)(sb + (size_t)(row0 + t*16 + lr)*1024 + kk + lg*8);
      #pragma unroll
      for (int t = 0; t < 4; t++)
        bfr[t] = *(const bf16x8*)(Wp + (size_t)(col0 + t*16 + lr)*1024 + kk + lg*8);
      #pragma unroll
      for (int a = 0; a < 2; a++)
        #pragma unroll
        for (int b = 0; b < 4; b++)
          acc[a][b] = MFMA16(afr[a], bfr[b], acc[a][b]);
    }
    #pragma unroll
    for (int a = 0; a < 2; a++)
      #pragma unroll
      for (int b = 0; b < 4; b++)
        #pragma unroll
        for (int r = 0; r < 4; r++) {
          int m = row0 + a*16 + lg*4 + r;
          int n = col0 + b*16 + lr;
          float v = acc[a][b][r];
          if (n < 1024)      { v = (v + bq[n]) * 0.125f; qb[(size_t)m*1024 + n] = f2bf(v); }
          else if (n < 2048) { kb[(size_t)m*1024 + (n-1024)] = f2bf(v); }
          else if (n < 3072) { vT[(size_t)(n-2048)*1024 + m] = f2bf(v); }
          else               { float sg = 1.f / (1.f + __expf(-v)); gb[(size_t)m*1024 + (n-3072)] = f2bf(sg); }
        }
  }
}

// ---------------- attention: swapped-QK^T flash over ALL j (no split), gated output ----
__global__ __launch_bounds__(256) void attn_kernel(
    const unsigned short* __restrict__ qb, const unsigned short* __restrict__ kb,
    const unsigned short* __restrict__ vT, const unsigned short* __restrict__ bias,
    const unsigned short* __restrict__ gb, unsigned short* __restrict__ og)
{
  __shared__ unsigned short P[4][1024];
  int lane = threadIdx.x & 63;
  int s = threadIdx.x >> 6;
  int jl = lane & 15, g = lane >> 4;
  int q0 = (blockIdx.x * 4 + s) * 16;
  int h = blockIdx.y;
  unsigned short* Pw = P[s];

  bf16x8 aq[2];
  #pragma unroll
  for (int kh = 0; kh < 2; kh++)
    aq[kh] = *(const bf16x8*)(qb + (size_t)(q0 + jl)*1024 + h*64 + kh*32 + g*8);

  f32x4 od[4] = {};
  float m = -1e30f, ss = 0.f;
  const unsigned short* bp = bias + ((size_t)h << 20);

  for (int jt = 0; jt < 1024; jt += 64) {
    f32x4 sc[4] = {};
    #pragma unroll
    for (int jb = 0; jb < 4; jb++)
      #pragma unroll
      for (int kh = 0; kh < 2; kh++) {
        bf16x8 bk = *(const bf16x8*)(kb + (size_t)(jt + jb*16 + jl)*1024 + h*64 + kh*32 + g*8);
        sc[jb] = MFMA16(bk, aq[kh], sc[jb]);   // swapped: per-lane q=jl, j varies
      }
    #pragma unroll
    for (int jb = 0; jb < 4; jb++) {
      ushort4 bl = *(const ushort4*)(bp + (size_t)(q0 + jl)*1024 + jt + jb*16 + g*4);
      sc[jb][0] += bf2f(bl.x); sc[jb][1] += bf2f(bl.y);
      sc[jb][2] += bf2f(bl.z); sc[jb][3] += bf2f(bl.w);
    }

    float mx = -1e30f;
    #pragma unroll
    for (int jb = 0; jb < 4; jb++)
      #pragma unroll
      for (int r = 0; r < 4; r++) mx = fmaxf(mx, sc[jb][r]);
    mx = fmaxf(mx, __shfl_xor(mx, 16));
    mx = fmaxf(mx, __shfl_xor(mx, 32));
    float mn = fmaxf(m, mx);
    float a = __expf(m - mn);
    m = mn;
    float rsum = 0.f;
    #pragma unroll
    for (int jb = 0; jb < 4; jb++) {
      short4 pk;
      float p0 = __expf(sc[jb][0] - mn); rsum += p0; pk.x = (short)f2bf(p0);
      float p1 = __expf(sc[jb][1] - mn); rsum += p1; pk.y = (short)f2bf(p1);
      float p2 = __expf(sc[jb][2] - mn); rsum += p2; pk.z = (short)f2bf(p2);
      float p3 = __expf(sc[jb][3] - mn); rsum += p3; pk.w = (short)f2bf(p3);
      int b = jb*2 + (g >> 1);
      int bpz = b ^ (jl & 7);
      *(short4*)(Pw + jl*64 + bpz*8 + (g & 1)*4) = pk;
    }
    ss = ss * a + rsum;   // per-lane quarter-partial over j (g-split)

    float albc[4];
    #pragma unroll
    for (int r = 0; r < 4; r++) albc[r] = __shfl(a, g*4 + r);
    #pragma unroll
    for (int db = 0; db < 4; db++)
      #pragma unroll
      for (int r = 0; r < 4; r++) od[db][r] *= albc[r];

    #pragma unroll
    for (int jh = 0; jh < 2; jh++) {
      int b = jh*4 + g;
      int bpz = b ^ (jl & 7);
      bf16x8 ap = *(const bf16x8*)(Pw + jl*64 + bpz*8);
      #pragma unroll
      for (int db = 0; db < 4; db++) {
        bf16x8 bv = *(const bf16x8*)(vT + (size_t)(h*64 + db*16 + jl)*1024 + jt + jh*32 + g*8);
        od[db] = MFMA16(ap, bv, od[db]);
      }
    }
  }

  // total row sum: reduce the 4 replicated lane-groups (same jl)
  ss += __shfl_xor(ss, 16);
  ss += __shfl_xor(ss, 32);
  float invb[4];
  #pragma unroll
  for (int r = 0; r < 4; r++)
    invb[r] = 1.f / __shfl(ss, g*4 + r);   // lane g*4+r holds total for q=q0+g*4+r

  #pragma unroll
  for (int db = 0; db < 4; db++)
    #pragma unroll
    for (int r = 0; r < 4; r++) {
      int q = q0 + g*4 + r;
      int d = h*64 + db*16 + jl;
      float gv = bf2f(gb[(size_t)q*1024 + d]);
      og[(size_t)q*1024 + d] = f2bf(od[db][r] * invb[r] * gv);
    }
}

// ---------------- output GEMM: (o*g) @ wo^T -> f32 ----------------
__global__ __launch_bounds__(256) void gemm_out(
    const unsigned short* __restrict__ A, const unsigned short* __restrict__ Bm,
    float* __restrict__ outF)
{
  int lane = threadIdx.x & 63;
  int w = threadIdx.x >> 6;
  int lr = lane & 15, lg = lane >> 4;
  int row0 = blockIdx.y * 64 + (w & 1) * 32;
  int col0 = blockIdx.x * 128 + (w >> 1) * 64;
  f32x4 acc[2][4] = {};
  for (int kk = 0; kk < 1024; kk += 32) {
    bf16x8 af[2], bfr[4];
    #pragma unroll
    for (int t = 0; t < 2; t++)
      af[t] = *(const bf16x8*)(A + (size_t)(row0 + t*16 + lr)*1024 + kk + lg*8);
    #pragma unroll
    for (int t = 0; t < 4; t++)
      bfr[t] = *(const bf16x8*)(Bm + (size_t)(col0 + t*16 + lr)*1024 + kk + lg*8);
    #pragma unroll
    for (int a = 0; a < 2; a++)
      #pragma unroll
      for (int b = 0; b < 4; b++)
        acc[a][b] = MFMA16(af[a], bfr[b], acc[a][b]);
  }
  #pragma unroll
  for (int a = 0; a < 2; a++)
    #pragma unroll
    for (int b = 0; b < 4; b++)
      #pragma unroll
      for (int r = 0; r < 4; r++) {
        int m = row0 + a*16 + lg*4 + r;
        int n = col0 + b*16 + lr;
        outF[(size_t)m * 1024 + n] = acc[a][b][r];
      }
}

extern "C" void kernel_launch(void* const* d_in, const int* in_sizes, int n_in,
                              void* d_out, int out_size, void* d_ws, size_t ws_size,
                              hipStream_t stream) {
  const float* s   = (const float*)d_in[0];
  const float* z   = (const float*)d_in[1];
  const float* wq  = (const float*)d_in[2];
  const float* bq  = (const float*)d_in[3];
  const float* wk  = (const float*)d_in[4];
  const float* wv  = (const float*)d_in[5];
  const float* wg  = (const float*)d_in[6];
  const float* znw = (const float*)d_in[7];
  const float* znb = (const float*)d_in[8];
  const float* wz  = (const float*)d_in[9];
  const float* wo  = (const float*)d_in[10];
  float* out = (float*)d_out;

  char* ws = (char*)d_ws;
  unsigned short* biasb = (unsigned short*)ws;                         // 32 MB (bf16)
  unsigned short* qbuf  = (unsigned short*)(ws + ((size_t)64 << 20));  // 2 MB
  unsigned short* kbuf  = (unsigned short*)(ws + ((size_t)66 << 20));  // 2 MB
  unsigned short* vTb   = (unsigned short*)(ws + ((size_t)68 << 20));  // 2 MB
  unsigned short* gbuf  = (unsigned short*)(ws + ((size_t)70 << 20));  // 2 MB
  unsigned short* ogb   = (unsigned short*)(ws + ((size_t)72 << 20));  // 2 MB
  unsigned short* sb    = (unsigned short*)(ws + ((size_t)74 << 20));  // 2 MB
  unsigned short* Wp    = (unsigned short*)(ws + ((size_t)76 << 20));  // 8 MB
  unsigned short* wob   = (unsigned short*)(ws + ((size_t)84 << 20));  // 2 MB
  unsigned short* wzp   = (unsigned short*)(ws + ((size_t)86 << 20));  // 4 KB
  float*          c12   = (float*)(ws + ((size_t)86 << 20) + 4096);    // 128 B

  prep_kernel<<<6145, 256, 0, stream>>>(s, wq, wk, wv, wg, wo, wz, znw, znb,
                                        sb, Wp, wob, wzp, c12);
  bias_gemm<<<1024, 256, 0, stream>>>(z, wzp, c12, biasb,
                                      sb, Wp, bq, qbuf, kbuf, vTb, gbuf);
  attn_kernel<<<dim3(16, 16), 256, 0, stream>>>(qbuf, kbuf, vTb, biasb, gbuf, ogb);
  gemm_out<<<dim3(8, 16), 256, 0, stream>>>(ogb, wob, out);
}

// Round 10
// 236.205 us; speedup vs baseline: 1.2916x; 1.0809x over previous
//
#include <hip/hip_runtime.h>
#include <hip/hip_bf16.h>

typedef __attribute__((ext_vector_type(8))) short bf16x8;
typedef __attribute__((ext_vector_type(4))) float f32x4;

#define MFMA16(a,b,c) __builtin_amdgcn_mfma_f32_16x16x32_bf16(a,b,c,0,0,0)

// Native HW conversion (v_cvt_pk_bf16_f32, RTNE) — replaces the 5-VALU bit-twiddle.
// m240: scalar casts are compiled to the packed HW converter; don't hand-write.
__device__ __forceinline__ unsigned short f2bf(float f){
  __hip_bfloat16 h = __float2bfloat16(f);
  unsigned short r;
  __builtin_memcpy(&r, &h, 2);
  return r;
}
__device__ __forceinline__ float bf2f(unsigned short u){
  return __uint_as_float(((unsigned int)u) << 16);
}

// ---------------- prep: f32 -> bf16 conversions (+ embedded wz prep) ----------------
__global__ __launch_bounds__(256) void prep_kernel(
    const float* __restrict__ s, const float* __restrict__ wq,
    const float* __restrict__ wk, const float* __restrict__ wv,
    const float* __restrict__ wg, const float* __restrict__ wo,
    const float* __restrict__ wz, const float* __restrict__ znw,
    const float* __restrict__ znb,
    unsigned short* __restrict__ sb, unsigned short* __restrict__ Wp,
    unsigned short* __restrict__ wob,
    unsigned short* __restrict__ wzp, float* __restrict__ c12)
{
  __shared__ float r1[256], r2[256];
  if (blockIdx.x == 6144) {
    int t = threadIdx.x; int h = t >> 4; int k0 = (t & 15) * 8;
    float p1 = 0.f, p2 = 0.f;
    for (int e = 0; e < 8; e++) {
      float wvv = wz[h*128 + k0 + e];
      float w = znw[k0 + e], b = znb[k0 + e];
      wzp[h*128 + k0 + e] = f2bf(wvv * w);
      p1 += wvv * w; p2 += wvv * b;
    }
    r1[t] = p1; r2[t] = p2;
    __syncthreads();
    if ((t & 15) == 0) {
      float s1 = 0.f, s2 = 0.f;
      for (int i = 0; i < 16; i++) { s1 += r1[t + i]; s2 += r2[t + i]; }
      c12[2*h] = s1; c12[2*h + 1] = s2;
    }
    return;
  }
  const size_t M1 = 1u << 20;
  size_t base = ((size_t)blockIdx.x * 256 + threadIdx.x) * 4;
  const float* src; unsigned short* dst; size_t off;
  if (base < M1) { src = s; dst = sb; off = base; }
  else if (base < 5*M1) {
    size_t r = base - M1; int wsel = (int)(r >> 20);
    const float* wsrc0 = (wsel == 0) ? wq : (wsel == 1) ? wk : (wsel == 2) ? wv : wg;
    src = wsrc0; dst = Wp + ((size_t)wsel << 20); off = r & (M1 - 1);
  } else { src = wo; dst = wob; off = base - 5*M1; }
  float4 v = *(const float4*)(src + off);
  ushort4 o4;
  o4.x = f2bf(v.x); o4.y = f2bf(v.y); o4.z = f2bf(v.z); o4.w = f2bf(v.w);
  *(ushort4*)(dst + off) = o4;
}

// ---------------- bf16 GEMM: C[M][N] = A[M][K] * B[N][K]^T ----------------
// wave tile 32x64 (acc 2x4); block = 4 waves (2 row x 2 col) = 64x128 tile
template<int MODE>
__global__ __launch_bounds__(256) void gemm_bf16(
    const unsigned short* __restrict__ A, const unsigned short* __restrict__ Bm,
    int M, int N, int K,
    const float* __restrict__ bq,
    unsigned short* __restrict__ qb, unsigned short* __restrict__ kb,
    unsigned short* __restrict__ vT, unsigned short* __restrict__ gb,
    float* __restrict__ outF)
{
  int lane = threadIdx.x & 63;
  int w = threadIdx.x >> 6;
  int lr = lane & 15, lg = lane >> 4;
  int row0 = blockIdx.y * 64 + (w & 1) * 32;
  int col0 = blockIdx.x * 128 + (w >> 1) * 64;
  f32x4 acc[2][4] = {};
  for (int kk = 0; kk < K; kk += 32) {
    bf16x8 af[2], bfr[4];
    #pragma unroll
    for (int t = 0; t < 2; t++)
      af[t] = *(const bf16x8*)(A + (size_t)(row0 + t*16 + lr) * K + kk + lg*8);
    #pragma unroll
    for (int t = 0; t < 4; t++)
      bfr[t] = *(const bf16x8*)(Bm + (size_t)(col0 + t*16 + lr) * K + kk + lg*8);
    #pragma unroll
    for (int a = 0; a < 2; a++)
      #pragma unroll
      for (int b = 0; b < 4; b++)
        acc[a][b] = MFMA16(af[a], bfr[b], acc[a][b]);
  }
  #pragma unroll
  for (int a = 0; a < 2; a++)
    #pragma unroll
    for (int b = 0; b < 4; b++)
      #pragma unroll
      for (int r = 0; r < 4; r++) {
        int m = row0 + a*16 + lg*4 + r;
        int n = col0 + b*16 + lr;
        float v = acc[a][b][r];
        if (MODE == 0) {
          if (n < 1024)      { v = (v + bq[n]) * 0.125f; qb[(size_t)m*1024 + n] = f2bf(v); }
          else if (n < 2048) { kb[(size_t)m*1024 + (n-1024)] = f2bf(v); }
          else if (n < 3072) { vT[(size_t)(n-2048)*1024 + m] = f2bf(v); }
          else               { float sg = 1.f / (1.f + __expf(-v)); gb[(size_t)m*1024 + (n-3072)] = f2bf(sg); }
        } else {
          outF[(size_t)m * N + n] = v;
        }
      }
}

// ---------------- fused bias + attention ----------------
// block = 16 waves (1024 thr) = all 16 heads for one 16-query tile, one j-quarter.
// phase A: wave w computes LN(z[q0+w, j, :]) . wz' bias into LDS biasT.
// phase B: wave w = head w does swapped-QK^T flash step with bias from LDS.
__global__ __launch_bounds__(1024, 4) void fused_attn(
    const unsigned short* __restrict__ qb, const unsigned short* __restrict__ kb,
    const unsigned short* __restrict__ vT, const float* __restrict__ z,
    const unsigned short* __restrict__ wzp, const float* __restrict__ c12,
    float* __restrict__ op, float* __restrict__ ml, float* __restrict__ ll)
{
  __shared__ float biasT[16][17][68];        // [h][q-local(pad17)][j-local]
  __shared__ unsigned short P[16][1024];     // per-wave P bounce, XOR-swizzled
  int w = threadIdx.x >> 6;                  // wave id = head = owned q-row
  int lane = threadIdx.x & 63;
  int jl = lane & 15, g = lane >> 4;
  int q0 = blockIdx.x * 16;
  int s = blockIdx.y;                        // j-quarter
  int h = w;
  unsigned short* Pw = P[w];

  bf16x8 af[4];
  #pragma unroll
  for (int mk = 0; mk < 4; mk++)
    af[mk] = *(const bf16x8*)(wzp + jl*128 + mk*32 + g*8);
  bf16x8 aq[2];
  #pragma unroll
  for (int kh = 0; kh < 2; kh++)
    aq[kh] = *(const bf16x8*)(qb + (size_t)(q0 + jl)*1024 + h*64 + kh*32 + g*8);
  float c1r[4], c2r[4];
  #pragma unroll
  for (int r = 0; r < 4; r++) {
    c1r[r] = c12[2*(g*4 + r)];
    c2r[r] = c12[2*(g*4 + r) + 1];
  }

  f32x4 od[4] = {};
  float m = -1e30f, ss = 0.f;

  #pragma unroll 1
  for (int t = 0; t < 4; t++) {
    int jt = s*256 + t*64;

    // ---------- phase A: bias fill for q-row q0+w, j in [jt, jt+64) ----------
    #pragma unroll 1
    for (int it = 0; it < 4; it++) {
      int j = jt + it*16 + jl;
      const float* zp = z + ((size_t)(q0 + w)*1024 + j)*128;
      bf16x8 tf[4];
      float sum = 0.f, sq = 0.f;
      #pragma unroll
      for (int mk = 0; mk < 4; mk++) {
        float4 a = *(const float4*)(zp + mk*32 + g*8);
        float4 b = *(const float4*)(zp + mk*32 + g*8 + 4);
        sum += a.x + a.y + a.z + a.w + b.x + b.y + b.z + b.w;
        sq = fmaf(a.x, a.x, fmaf(a.y, a.y, fmaf(a.z, a.z, fmaf(a.w, a.w, sq))));
        sq = fmaf(b.x, b.x, fmaf(b.y, b.y, fmaf(b.z, b.z, fmaf(b.w, b.w, sq))));
        bf16x8 tv;
        tv[0] = (short)f2bf(a.x); tv[1] = (short)f2bf(a.y);
        tv[2] = (short)f2bf(a.z); tv[3] = (short)f2bf(a.w);
        tv[4] = (short)f2bf(b.x); tv[5] = (short)f2bf(b.y);
        tv[6] = (short)f2bf(b.z); tv[7] = (short)f2bf(b.w);
        tf[mk] = tv;
      }
      sum += __shfl_xor(sum, 16); sum += __shfl_xor(sum, 32);
      sq  += __shfl_xor(sq, 16);  sq  += __shfl_xor(sq, 32);
      float mu = sum * (1.f/128.f);
      float rs = rsqrtf(sq * (1.f/128.f) - mu*mu + 1e-5f);
      f32x4 D = {0.f, 0.f, 0.f, 0.f};
      #pragma unroll
      for (int mk = 0; mk < 4; mk++)
        D = MFMA16(af[mk], tf[mk], D);
      #pragma unroll
      for (int r = 0; r < 4; r++)
        biasT[g*4 + r][w][it*16 + jl] = rs*(D[r] - mu*c1r[r]) + c2r[r];
    }
    __syncthreads();

    // ---------- phase B: attention on this 64-j tile, head h ----------
    f32x4 sc[4] = {};
    #pragma unroll
    for (int jb = 0; jb < 4; jb++)
      #pragma unroll
      for (int kh = 0; kh < 2; kh++) {
        bf16x8 bk = *(const bf16x8*)(kb + (size_t)(jt + jb*16 + jl)*1024 + h*64 + kh*32 + g*8);
        sc[jb] = MFMA16(bk, aq[kh], sc[jb]);   // swapped: rows=j, cols=q
      }
    #pragma unroll
    for (int jb = 0; jb < 4; jb++) {
      f32x4 bl = *(const f32x4*)(&biasT[h][jl][jb*16 + g*4]);
      sc[jb][0] += bl[0]; sc[jb][1] += bl[1];
      sc[jb][2] += bl[2]; sc[jb][3] += bl[3];
    }

    float mx = -1e30f;
    #pragma unroll
    for (int jb = 0; jb < 4; jb++)
      #pragma unroll
      for (int r = 0; r < 4; r++) mx = fmaxf(mx, sc[jb][r]);
    mx = fmaxf(mx, __shfl_xor(mx, 16));
    mx = fmaxf(mx, __shfl_xor(mx, 32));
    float mn = fmaxf(m, mx);
    float a = __expf(m - mn);
    m = mn;
    float rsum = 0.f;
    #pragma unroll
    for (int jb = 0; jb < 4; jb++) {
      short4 pk;
      float p0 = __expf(sc[jb][0] - mn); rsum += p0; pk.x = (short)f2bf(p0);
      float p1 = __expf(sc[jb][1] - mn); rsum += p1; pk.y = (short)f2bf(p1);
      float p2 = __expf(sc[jb][2] - mn); rsum += p2; pk.z = (short)f2bf(p2);
      float p3 = __expf(sc[jb][3] - mn); rsum += p3; pk.w = (short)f2bf(p3);
      int b = jb*2 + (g >> 1);
      int bpz = b ^ (jl & 7);
      *(short4*)(Pw + jl*64 + bpz*8 + (g & 1)*4) = pk;
    }
    ss = ss * a + rsum;   // per-lane quarter-partial (reduced over g at the end)

    float albc[4];
    #pragma unroll
    for (int r = 0; r < 4; r++) albc[r] = __shfl(a, g*4 + r);
    #pragma unroll
    for (int db = 0; db < 4; db++)
      #pragma unroll
      for (int r = 0; r < 4; r++) od[db][r] *= albc[r];

    #pragma unroll
    for (int jh = 0; jh < 2; jh++) {
      int b = jh*4 + g;
      int bpz = b ^ (jl & 7);
      bf16x8 ap = *(const bf16x8*)(Pw + jl*64 + bpz*8);
      #pragma unroll
      for (int db = 0; db < 4; db++) {
        bf16x8 bv = *(const bf16x8*)(vT + (size_t)(h*64 + db*16 + jl)*1024 + jt + jh*32 + g*8);
        od[db] = MFMA16(ap, bv, od[db]);
      }
    }
    __syncthreads();   // biasT reused next tile
  }

  // reduce ss across the 4 replicated lane-groups (same jl)
  ss += __shfl_xor(ss, 16);
  ss += __shfl_xor(ss, 32);

  size_t base = ((size_t)(s*16 + h) * 1024);
  #pragma unroll
  for (int db = 0; db < 4; db++)
    #pragma unroll
    for (int r = 0; r < 4; r++) {
      int q = q0 + g*4 + r;
      op[(base + q)*64 + db*16 + jl] = od[db][r];
    }
  if (g == 0) {
    ml[base + q0 + jl] = m;
    ll[base + q0 + jl] = ss;
  }
}

// ---------------- combine: merge 4 j-split partials, gate, bf16 ----------------
__global__ __launch_bounds__(256) void combine_kernel(
    const float* __restrict__ op, const float* __restrict__ ml,
    const float* __restrict__ ll, const unsigned short* __restrict__ gb,
    unsigned short* __restrict__ og)
{
  int t = blockIdx.x * 256 + threadIdx.x;   // over 16h * 1024q * 16d4
  int d4 = t & 15;
  int q = (t >> 4) & 1023;
  int h = t >> 14;

  float mv[4], lv[4];
  float mstar = -1e30f;
  #pragma unroll
  for (int s = 0; s < 4; s++) {
    mv[s] = ml[(size_t)(s*16 + h)*1024 + q];
    lv[s] = ll[(size_t)(s*16 + h)*1024 + q];
    mstar = fmaxf(mstar, mv[s]);
  }
  float lsum = 0.f;
  float ws[4];
  #pragma unroll
  for (int s = 0; s < 4; s++) {
    ws[s] = __expf(mv[s] - mstar);
    lsum = fmaf(ws[s], lv[s], lsum);
  }
  float inv = 1.f / lsum;

  float4 o = {0.f, 0.f, 0.f, 0.f};
  #pragma unroll
  for (int s = 0; s < 4; s++) {
    float4 p = *(const float4*)(op + ((size_t)(s*16 + h)*1024 + q)*64 + d4*4);
    o.x = fmaf(ws[s], p.x, o.x); o.y = fmaf(ws[s], p.y, o.y);
    o.z = fmaf(ws[s], p.z, o.z); o.w = fmaf(ws[s], p.w, o.w);
  }
  ushort4 gv = *(const ushort4*)(gb + (size_t)q*1024 + h*64 + d4*4);
  ushort4 r;
  r.x = f2bf(o.x * inv * bf2f(gv.x));
  r.y = f2bf(o.y * inv * bf2f(gv.y));
  r.z = f2bf(o.z * inv * bf2f(gv.z));
  r.w = f2bf(o.w * inv * bf2f(gv.w));
  *(ushort4*)(og + (size_t)q*1024 + h*64 + d4*4) = r;
}

extern "C" void kernel_launch(void* const* d_in, const int* in_sizes, int n_in,
                              void* d_out, int out_size, void* d_ws, size_t ws_size,
                              hipStream_t stream) {
  const float* s   = (const float*)d_in[0];
  const float* z   = (const float*)d_in[1];
  const float* wq  = (const float*)d_in[2];
  const float* bq  = (const float*)d_in[3];
  const float* wk  = (const float*)d_in[4];
  const float* wv  = (const float*)d_in[5];
  const float* wg  = (const float*)d_in[6];
  const float* znw = (const float*)d_in[7];
  const float* znb = (const float*)d_in[8];
  const float* wz  = (const float*)d_in[9];
  const float* wo  = (const float*)d_in[10];
  float* out = (float*)d_out;

  char* ws = (char*)d_ws;
  unsigned short* qbuf  = (unsigned short*)(ws + ((size_t)64 << 20));  // 2 MB
  unsigned short* kbuf  = (unsigned short*)(ws + ((size_t)66 << 20));  // 2 MB
  unsigned short* vTb   = (unsigned short*)(ws + ((size_t)68 << 20));  // 2 MB
  unsigned short* gbuf  = (unsigned short*)(ws + ((size_t)70 << 20));  // 2 MB
  unsigned short* ogb   = (unsigned short*)(ws + ((size_t)72 << 20));  // 2 MB
  unsigned short* sb    = (unsigned short*)(ws + ((size_t)74 << 20));  // 2 MB
  unsigned short* Wp    = (unsigned short*)(ws + ((size_t)76 << 20));  // 8 MB
  unsigned short* wob   = (unsigned short*)(ws + ((size_t)84 << 20));  // 2 MB
  unsigned short* wzp   = (unsigned short*)(ws + ((size_t)86 << 20));  // 4 KB
  float*          c12   = (float*)(ws + ((size_t)86 << 20) + 4096);    // 128 B
  float*          opart = (float*)(ws + ((size_t)96 << 20));           // 16 MB
  float*          mlb   = (float*)(ws + ((size_t)112 << 20));          // 256 KB
  float*          llb   = (float*)(ws + ((size_t)113 << 20));          // 256 KB

  prep_kernel<<<6145, 256, 0, stream>>>(s, wq, wk, wv, wg, wo, wz, znw, znb,
                                        sb, Wp, wob, wzp, c12);
  gemm_bf16<0><<<dim3(32, 16), 256, 0, stream>>>(sb, Wp, 1024, 4096, 1024, bq,
                                                 qbuf, kbuf, vTb, gbuf, nullptr);
  fused_attn<<<dim3(64, 4), 1024, 0, stream>>>(qbuf, kbuf, vTb, z, wzp, c12,
                                               opart, mlb, llb);
  combine_kernel<<<1024, 256, 0, stream>>>(opart, mlb, llb, gbuf, ogb);
  gemm_bf16<1><<<dim3(8, 16), 256, 0, stream>>>(ogb, wob, 1024, 1024, 1024, nullptr,
                                                nullptr, nullptr, nullptr, nullptr, out);
}